// Round 10
// baseline (198.137 us; speedup 1.0000x reference)
//
#include <hip/hip_runtime.h>
#include <hip/hip_bf16.h>

#define B_  2
#define S_  2048
#define D_  1024
#define H_  16
#define HD_ 64
#define M_  (B_*S_)   // 4096

using bf16x8 = __attribute__((ext_vector_type(8))) short;
using f32x4  = __attribute__((ext_vector_type(4))) float;
using f32x16 = __attribute__((ext_vector_type(16))) float;
using u32x4  = __attribute__((ext_vector_type(4))) unsigned int;
using uint2v = __attribute__((ext_vector_type(2))) unsigned int;

static __device__ __forceinline__ ushort f2bf(float f) {
    __hip_bfloat16 h = __float2bfloat16(f);
    return *reinterpret_cast<ushort*>(&h);
}
static __device__ __forceinline__ float max3f(float a, float b, float c) {
    return fmaxf(fmaxf(a, b), c);   // clang fuses to v_max3_f32
}
// native exp2 (v_exp_f32): args here are finite and <= +8, so no fixup path needed
static __device__ __forceinline__ float fexp2(float x) {
#if __has_builtin(__builtin_amdgcn_exp2f)
    return __builtin_amdgcn_exp2f(x);
#else
    return exp2f(x);
#endif
}
// branchless RNE bf16 pair-pack (valid for non-NaN inputs; P = exp2(<=8) is never NaN)
static __device__ __forceinline__ unsigned int pack_bf16(float p0, float p1) {
    unsigned int a = __float_as_uint(p0), b = __float_as_uint(p1);
    a += 0x7fffu + ((a >> 16) & 1u);
    b += 0x7fffu + ((b >> 16) & 1u);
    return (a >> 16) | (b & 0xffff0000u);
}

// async global->LDS, 16B per lane; LDS dest = wave-uniform base + lane*16
#define GLDS16(gp, lp) __builtin_amdgcn_global_load_lds( \
    (const __attribute__((address_space(1))) void*)(gp), \
    (__attribute__((address_space(3))) void*)(lp), 16, 0, 0)

// ------- prep: z<4 -> transpose one fp32 [1024][1024] weight to bf16 [C][R];
//         z==4 -> convert x fp32 -> bf16 (same layout). One launch total. -------
__global__ void prep(const float* __restrict__ x,
                     const float* __restrict__ wq, const float* __restrict__ wk,
                     const float* __restrict__ wv, const float* __restrict__ wo,
                     ushort* __restrict__ xb, ushort* __restrict__ wqkvT, ushort* __restrict__ woT) {
    const int z = blockIdx.z;
    if (z == 4) {
        int blk = blockIdx.y * 32 + blockIdx.x;          // 0..1023
        int tid = threadIdx.y * 32 + threadIdx.x;        // 0..255
        #pragma unroll
        for (int q = 0; q < 4; q++) {
            int i = ((q * 1024 + blk) * 256 + tid) * 4;  // covers 4M floats
            float4 v = *reinterpret_cast<const float4*>(x + i);
            ushort4 o;
            o.x = f2bf(v.x); o.y = f2bf(v.y); o.z = f2bf(v.z); o.w = f2bf(v.w);
            *reinterpret_cast<ushort4*>(xb + i) = o;
        }
        return;
    }
    const float* src = (z == 0) ? wq : (z == 1) ? wk : (z == 2) ? wv : wo;
    ushort* dst = (z < 3) ? (wqkvT + (size_t)z * 1024 * 1024) : woT;
    const int R = 1024, C = 1024;
    __shared__ float t[32][33];
    int c0 = blockIdx.x * 32, r0 = blockIdx.y * 32;
    int tx = threadIdx.x, ty = threadIdx.y;
    #pragma unroll
    for (int i = 0; i < 4; i++)
        t[ty + i*8][tx] = src[(size_t)(r0 + ty + i*8) * C + c0 + tx];
    __syncthreads();
    #pragma unroll
    for (int i = 0; i < 4; i++)
        dst[(size_t)(c0 + ty + i*8) * R + r0 + tx] = f2bf(t[tx][ty + i*8]);
}

// ---------------- GEMM: C = A(bf16 [M][K]) * Bt(bf16 [N][K])^T ----------------
// Round 10 (= round 9 resubmit; round 9 never ran: container infra failure).
// DOUBLE-BUFFERED BK=32 (As[2]+Bs[2] = 32 KB MODE0 / 24 KB MODE1 -> keeps
// 3 blocks/CU) with the attn-proven 2-phase pattern: stage(next) || compute(cur),
// one barrier per K-tile, loads in flight across the whole compute phase.
// 64B LDS rows (4 x 16B slots): swizzle slot ^= (row>>1)&3 -> 2-way aliasing (free);
// inverse swizzle folded into the per-lane global source (rule #21), 4-lane groups
// still cover contiguous 64B -> coalescing intact.
// Epilogues byte-identical to round 8 (harness-proven).
// MODE 0 (NJ=4): QKV epilogue; V written directly transposed to [bh][hd][s].
// MODE 1 (NJ=2): fp32 out + bias, BN=64 -> 512 blocks.
template<int MODE, int NJ>
__launch_bounds__(256, 3)
__global__ void gemm_bt(const ushort* __restrict__ A, const ushort* __restrict__ Bt,
                        int Mdim, int Ndim, int Kdim,
                        ushort* __restrict__ qout, ushort* __restrict__ kout, ushort* __restrict__ vout,
                        const float* __restrict__ bq, const float* __restrict__ bk, const float* __restrict__ bv,
                        float* __restrict__ out, const float* __restrict__ bias)
{
    constexpr int BN = NJ * 32;
    __shared__ __align__(16) ushort As[2][128][32];   // 2 x 8 KB, swizzled 16B slots
    __shared__ __align__(16) ushort Bs[2][BN][32];    // 2 x 8 or 4 KB
    const int tid  = threadIdx.x;
    const int lane = tid & 63, wave = tid >> 6;
    const int wm = wave & 1, wn = wave >> 1;       // 2x2 waves
    // XCD-chunked remap: 8 consecutive lin -> 8 XCDs; contiguous super-tile per XCD.
    const int lin = blockIdx.x;
    const int xcd = lin & 7, idx = lin >> 3;
    int my, nx;
    if (MODE == 0) { my = (xcd >> 1) * 8 + idx / 12; nx = (xcd & 1) * 12 + idx % 12; }  // 8m x 12n per XCD
    else           { my = xcd * 4 + (idx >> 4);      nx = idx & 15; }                   // 4m x 16n per XCD
    const int m0 = my * 128, n0 = nx * BN;
    const int g = lane >> 4, c = lane & 15;

    f32x4 acc[4][NJ];
    #pragma unroll
    for (int i = 0; i < 4; i++)
        #pragma unroll
        for (int j = 0; j < NJ; j++) acc[i][j] = (f32x4){0.f, 0.f, 0.f, 0.f};

    // staging: 1 GLDS16 = 16 rows x 64B; lane l -> LDS (row = l>>2, slot = l&3).
    // Want LDS[row][slot] = G[row][slot ^ ((row>>1)&3)] -> lane-local f = (l>>3)&3.
    const int arow  = lane >> 2;                         // 0..15 within 16-row chunk
    const int aslot = (lane & 3) ^ ((lane >> 3) & 3);    // inverse-swizzled 16B slot
    const ushort* Ag = A  + (size_t)(m0 + arow) * Kdim + aslot * 8;
    const ushort* Bg = Bt + (size_t)(n0 + arow) * Kdim + aslot * 8;

    auto stage = [&](int buf, int kt) {
        #pragma unroll
        for (int p = 0; p < 2; p++) {
            int ch = wave + p * 4;               // 8 A-chunks of 16 rows over 4 waves
            GLDS16(Ag + (size_t)(ch*16) * Kdim + kt, &As[buf][ch*16][0]);
        }
        #pragma unroll
        for (int p = 0; p < NJ/2; p++) {
            int ch = wave + p * 4;               // NJ*2 B-chunks over 4 waves
            GLDS16(Bg + (size_t)(ch*16) * Kdim + kt, &Bs[buf][ch*16][0]);
        }
    };

    auto compute = [&](int buf) {
        bf16x8 af[4], bfr[NJ];
        const int sl = (g ^ ((c >> 1) & 3)) * 8;   // de-swizzle: (row>>1)&3 == (c>>1)&3
        #pragma unroll
        for (int t = 0; t < 4; t++)
            af[t] = *reinterpret_cast<const bf16x8*>(&As[buf][wm*64 + t*16 + c][sl]);
        #pragma unroll
        for (int t = 0; t < NJ; t++)
            bfr[t] = *reinterpret_cast<const bf16x8*>(&Bs[buf][wn*(NJ*16) + t*16 + c][sl]);
        #pragma unroll
        for (int i = 0; i < 4; i++)
            #pragma unroll
            for (int j = 0; j < NJ; j++)
                acc[i][j] = __builtin_amdgcn_mfma_f32_16x16x32_bf16(af[i], bfr[j], acc[i][j], 0, 0, 0);
    };

    // 2-phase pipelined K-loop: tile t in buf t&1; one barrier per tile, prefetch in flight.
    const int NT = Kdim >> 5;   // BK=32
    stage(0, 0);
    __syncthreads();
    #pragma unroll 1
    for (int it = 0; it < NT - 1; ++it) {
        stage((it + 1) & 1, (it + 1) * 32);
        compute(it & 1);
        __syncthreads();                 // next tile landed (issued a full compute ago)
    }
    compute((NT - 1) & 1);

    // ---- epilogue: which and h are BLOCK-uniform (tiles never straddle 1024-col lines) ----
    const float qscale = 0.125f * 1.4426950408889634f;  // att_scale * log2e (exp2 softmax)
    if (MODE == 0) {
        const int which = n0 >> 10;                      // 0=q 1=k 2=v (uniform)
        const int cc0 = (n0 & 1023) + wn*64;             // multiple of 64
        const int h = cc0 >> 6;                          // uniform head
        const int b = m0 >> 11;                          // uniform batch (128 | 2048)
        if (which == 2) {
            // ---- V: direct transposed store [bh][hd][s], ushort4 along s ----
            float bj[4];
            #pragma unroll
            for (int j = 0; j < 4; j++) bj[j] = bv[cc0 + j*16 + c];
            const int sbase = (m0 & 2047) + wm*64 + g*4;
            ushort* vb = vout + (size_t)(b*H_ + h) * HD_ * S_;
            #pragma unroll
            for (int i = 0; i < 4; i++) {
                int s0 = sbase + i*16;
                #pragma unroll
                for (int j = 0; j < 4; j++) {
                    int hd = j*16 + c;
                    ushort4 o;
                    o.x = f2bf(acc[i][j][0] + bj[j]);
                    o.y = f2bf(acc[i][j][1] + bj[j]);
                    o.z = f2bf(acc[i][j][2] + bj[j]);
                    o.w = f2bf(acc[i][j][3] + bj[j]);
                    *reinterpret_cast<ushort4*>(vb + (size_t)hd * S_ + s0) = o;
                }
            }
        } else {
            ushort* dst0 = (which == 0) ? qout : kout;
            const float* bp = (which == 0) ? bq : bk;
            const float scl = (which == 0) ? qscale : 1.f;
            float bj[4];
            #pragma unroll
            for (int j = 0; j < 4; j++) bj[j] = bp[cc0 + j*16 + c];
            #pragma unroll
            for (int i = 0; i < 4; i++) {
                #pragma unroll
                for (int r = 0; r < 4; r++) {
                    int row = m0 + wm*64 + i*16 + g*4 + r;   // C/D: row=(lane>>4)*4+reg
                    int s = row & 2047;
                    ushort* orow = dst0 + (((size_t)(b*H_ + h)) * S_ + s) * HD_;
                    #pragma unroll
                    for (int j = 0; j < 4; j++)
                        orow[j*16 + c] = f2bf((acc[i][j][r] + bj[j]) * scl);
                }
            }
        }
    } else {
        float bj[NJ];
        #pragma unroll
        for (int j = 0; j < NJ; j++) bj[j] = bias[n0 + wn*(NJ*16) + j*16 + c];
        #pragma unroll
        for (int i = 0; i < 4; i++)
            #pragma unroll
            for (int r = 0; r < 4; r++) {
                int row = m0 + wm*64 + i*16 + g*4 + r;
                float* orow = out + (size_t)row * Ndim + n0 + wn*(NJ*16);
                #pragma unroll
                for (int j = 0; j < NJ; j++)
                    orow[j*16 + c] = acc[i][j][r] + bj[j];
            }
    }
}

// ---------------- flash attention: in-block split-K + 2-tile interleave ----------------
// (unchanged from round-5..8 passing kernel: ~63 us steady-state)
__launch_bounds__(512, 4)
__global__ void attn_kernel(const ushort* __restrict__ Q, const ushort* __restrict__ K,
                            const ushort* __restrict__ Vt, ushort* __restrict__ O)
{
    __shared__ __align__(16) ushort Ks[2][2][64][64];   // [grp][buf][key][hd], swizzled
    __shared__ __align__(16) ushort Vs[2][2][64][64];   // [grp][buf][hd][key], swizzled
    const int tid = threadIdx.x, lane = tid & 63, w = tid >> 6;
    const int grp = w >> 2, wq4 = w & 3;                 // key-half group, q-wave within it
    const int q31 = lane & 31, hi = lane >> 5, x7 = lane & 7;

    // T1: group 4 consecutive bh per XCD so K/V (4*512KB=2MB) stay L2-resident
    int lin = blockIdx.x + gridDim.x * blockIdx.y;   // 0..511
    int xcd = lin & 7, idx = lin >> 3;
    int bh = xcd * 4 + (idx & 3);
    int qb = idx >> 2;                                // 0..15
    const int q0 = qb * 128;
    const int kt_base = grp * 1024;
    const ushort* Kp = K  + (size_t)bh * S_ * HD_;   // [s][hd]
    const ushort* Vp = Vt + (size_t)bh * HD_ * S_;   // [hd][s]

    // Q B-fragments (pre-scaled by 0.125*log2e): B[col=q31][k = hi*8+j], 4 hd-chunks
    bf16x8 qf[4];
    #pragma unroll
    for (int c4 = 0; c4 < 4; c4++)
        qf[c4] = *reinterpret_cast<const bf16x8*>(
            Q + (size_t)bh * S_ * HD_ + (size_t)(q0 + wq4*32 + q31) * HD_ + c4*16 + hi*8);

    f32x16 acc0, acc1;          // O^T: row = hd', col = q31 (acc0: hd 0-31, acc1: 32-63)
    #pragma unroll
    for (int r = 0; r < 16; r++) { acc0[r] = 0.f; acc1[r] = 0.f; }
    float m_i = -INFINITY, l_i = 0.f;

    // staging geometry: per wave 8 rows x 128B per GLDS16; swizzle folded into global src
    const int srow  = lane >> 3;              // 0..7 within chunk
    const int sslot = (lane & 7) ^ srow;      // inverse-swizzled 16B slot
    const ushort* kg = Kp + (size_t)srow * HD_ + sslot * 8;
    const ushort* vg = Vp + (size_t)srow * S_  + sslot * 8;

    auto stage = [&](int buf, int kt) {       // group's 4 waves cover 8 chunks x 8 rows
        #pragma unroll
        for (int p = 0; p < 2; p++) {
            int ch = wq4 + p * 4;
            GLDS16(kg + (size_t)(kt + ch*8) * HD_, &Ks[grp][buf][ch*8][0]);
            GLDS16(vg + (size_t)(ch*8) * S_ + kt,  &Vs[grp][buf][ch*8][0]);
        }
    };

    // softmax + in-register repack for one 32-key tile
    auto softmax_pack = [&](const f32x16& st, bf16x8& pf0, bf16x8& pf1) {
        float g0 = max3f(st[0],  st[1],  st[2]);
        float g1 = max3f(st[3],  st[4],  st[5]);
        float g2 = max3f(st[6],  st[7],  st[8]);
        float g3 = max3f(st[9],  st[10], st[11]);
        float g4 = max3f(st[12], st[13], st[14]);
        float pm = fmaxf(max3f(g0, g1, g2), max3f(g3, g4, st[15]));
#if __has_builtin(__builtin_amdgcn_permlane32_swap)
        {
            uint2v r = __builtin_amdgcn_permlane32_swap(__float_as_uint(pm), __float_as_uint(pm), false, false);
            pm = fmaxf(__uint_as_float(r.x), __uint_as_float(r.y));
        }
#else
        pm = fmaxf(pm, __shfl_xor(pm, 32));
#endif
        if (__any(pm > m_i + 8.f)) {          // T13 defer-max (exp2 domain)
            float mnew = fmaxf(m_i, pm);
            float al = fexp2(m_i - mnew);
            l_i *= al;
            #pragma unroll
            for (int r = 0; r < 16; r++) { acc0[r] *= al; acc1[r] *= al; }
            m_i = mnew;
        }
        float rs = 0.f;
        unsigned int dd[8];
        #pragma unroll
        for (int r2 = 0; r2 < 8; r2++) {
            float p0 = fexp2(st[r2*2]     - m_i);
            float p1 = fexp2(st[r2*2 + 1] - m_i);
            rs += p0 + p1;
            dd[r2] = pack_bf16(p0, p1);
        }
#if __has_builtin(__builtin_amdgcn_permlane32_swap)
        {
            uint2v r = __builtin_amdgcn_permlane32_swap(__float_as_uint(rs), __float_as_uint(rs), false, false);
            rs = __uint_as_float(r.x) + __uint_as_float(r.y);
        }
#else
        rs += __shfl_xor(rs, 32);
#endif
        l_i += rs;
        u32x4 t0, t1;
#if __has_builtin(__builtin_amdgcn_permlane32_swap)
        {
            uint2v s02 = __builtin_amdgcn_permlane32_swap(dd[0], dd[2], false, false);
            uint2v s13 = __builtin_amdgcn_permlane32_swap(dd[1], dd[3], false, false);
            uint2v s46 = __builtin_amdgcn_permlane32_swap(dd[4], dd[6], false, false);
            uint2v s57 = __builtin_amdgcn_permlane32_swap(dd[5], dd[7], false, false);
            t0 = (u32x4){s02.x, s13.x, s02.y, s13.y};
            t1 = (u32x4){s46.x, s57.x, s46.y, s57.y};
        }
#else
        {
            unsigned int ee[8];
            #pragma unroll
            for (int r2 = 0; r2 < 8; r2++)
                ee[r2] = (unsigned int)__shfl_xor((int)dd[r2], 32);
            t0 = (u32x4){ hi ? ee[2] : dd[0], hi ? ee[3] : dd[1],
                          hi ? dd[2] : ee[0], hi ? dd[3] : ee[1] };
            t1 = (u32x4){ hi ? ee[6] : dd[4], hi ? ee[7] : dd[5],
                          hi ? dd[6] : ee[4], hi ? dd[7] : ee[5] };
        }
#endif
        pf0 = *reinterpret_cast<bf16x8*>(&t0);
        pf1 = *reinterpret_cast<bf16x8*>(&t1);
    };

    auto compute64 = [&](int buf) {
        const ushort (*ks)[64] = Ks[grp][buf];
        const ushort (*vs)[64] = Vs[grp][buf];
        // ---- QK^T for BOTH 32-key tiles up front (MFMA latency hides under sm(t0)) ----
        f32x16 st0, st1;
        #pragma unroll
        for (int r = 0; r < 16; r++) { st0[r] = 0.f; st1[r] = 0.f; }
        __builtin_amdgcn_s_setprio(1);
        #pragma unroll
        for (int c4 = 0; c4 < 4; c4++) {
            bf16x8 kf = *reinterpret_cast<const bf16x8*>(&ks[q31][((c4*2 + hi) ^ x7) * 8]);
            st0 = __builtin_amdgcn_mfma_f32_32x32x16_bf16(kf, qf[c4], st0, 0, 0, 0);
        }
        #pragma unroll
        for (int c4 = 0; c4 < 4; c4++) {
            bf16x8 kf = *reinterpret_cast<const bf16x8*>(&ks[32 + q31][((c4*2 + hi) ^ x7) * 8]);
            st1 = __builtin_amdgcn_mfma_f32_32x32x16_bf16(kf, qf[c4], st1, 0, 0, 0);
        }
        __builtin_amdgcn_s_setprio(0);

        // ---- tile 0: softmax (overlaps st1 MFMA), then PV ----
        bf16x8 pf0, pf1;
        softmax_pack(st0, pf0, pf1);
        {
            bf16x8 vf0 = *reinterpret_cast<const bf16x8*>(&vs[q31]     [((0 + hi) ^ x7) * 8]);
            bf16x8 vf1 = *reinterpret_cast<const bf16x8*>(&vs[q31]     [((2 + hi) ^ x7) * 8]);
            bf16x8 vf2 = *reinterpret_cast<const bf16x8*>(&vs[32 + q31][((0 + hi) ^ x7) * 8]);
            bf16x8 vf3 = *reinterpret_cast<const bf16x8*>(&vs[32 + q31][((2 + hi) ^ x7) * 8]);
            __builtin_amdgcn_s_setprio(1);
            acc0 = __builtin_amdgcn_mfma_f32_32x32x16_bf16(vf0, pf0, acc0, 0, 0, 0);
            acc0 = __builtin_amdgcn_mfma_f32_32x32x16_bf16(vf1, pf1, acc0, 0, 0, 0);
            acc1 = __builtin_amdgcn_mfma_f32_32x32x16_bf16(vf2, pf0, acc1, 0, 0, 0);
            acc1 = __builtin_amdgcn_mfma_f32_32x32x16_bf16(vf3, pf1, acc1, 0, 0, 0);
            __builtin_amdgcn_s_setprio(0);
        }
        // ---- tile 1: softmax (overlaps PV(t0) MFMA), then PV ----
        softmax_pack(st1, pf0, pf1);
        {
            bf16x8 vf0 = *reinterpret_cast<const bf16x8*>(&vs[q31]     [((4 + hi) ^ x7) * 8]);
            bf16x8 vf1 = *reinterpret_cast<const bf16x8*>(&vs[q31]     [((6 + hi) ^ x7) * 8]);
            bf16x8 vf2 = *reinterpret_cast<const bf16x8*>(&vs[32 + q31][((4 + hi) ^ x7) * 8]);
            bf16x8 vf3 = *reinterpret_cast<const bf16x8*>(&vs[32 + q31][((6 + hi) ^ x7) * 8]);
            __builtin_amdgcn_s_setprio(1);
            acc0 = __builtin_amdgcn_mfma_f32_32x32x16_bf16(vf0, pf0, acc0, 0, 0, 0);
            acc0 = __builtin_amdgcn_mfma_f32_32x32x16_bf16(vf1, pf1, acc0, 0, 0, 0);
            acc1 = __builtin_amdgcn_mfma_f32_32x32x16_bf16(vf2, pf0, acc1, 0, 0, 0);
            acc1 = __builtin_amdgcn_mfma_f32_32x32x16_bf16(vf3, pf1, acc1, 0, 0, 0);
            __builtin_amdgcn_s_setprio(0);
        }
    };

    // ---- 2-phase pipelined main loop over this group's 1024 keys (16 x 64) ----
    stage(0, kt_base);
    __syncthreads();
    #pragma unroll 1
    for (int it = 0; it < 15; ++it) {
        stage((it & 1) ^ 1, kt_base + (it + 1) * 64);
        compute64(it & 1);
        __syncthreads();                 // drains vmcnt (next tile arrived) + protects reuse
    }
    compute64(1);

    // ---- cross-group merge via LDS (lane-aligned: partner lane = same (q, hd-set)) ----
    __syncthreads();                     // everyone done reading K/V LDS
    float* fb = (wq4 < 2) ? reinterpret_cast<float*>(&Ks[0][0][0][0])
                          : reinterpret_cast<float*>(&Vs[0][0][0][0]);
    const int slot = ((wq4 & 1) * 64 + lane) * 35;   // 35: odd stride, conflict-light
    if (grp == 1) {
        #pragma unroll
        for (int r = 0; r < 16; r++) { fb[slot + r] = acc0[r]; fb[slot + 16 + r] = acc1[r]; }
        fb[slot + 32] = m_i;
        fb[slot + 33] = l_i;
    }
    __syncthreads();
    if (grp == 0) {
        float m2 = fb[slot + 32], l2 = fb[slot + 33];
        float mm = fmaxf(m_i, m2);
        float a1 = fexp2(m_i - mm), a2 = fexp2(m2 - mm);
        float inv = 1.f / (l_i * a1 + l2 * a2);
        const int b = bh >> 4, h = bh & 15;
        const int s = q0 + wq4*32 + q31;
        ushort* op = O + (size_t)(b*S_ + s) * 1024 + h*64;
        #pragma unroll
        for (int rg = 0; rg < 4; rg++) {
            int hd0 = rg*8 + hi*4;
            ushort4 o;
            o.x = f2bf((acc0[rg*4+0]*a1 + fb[slot + rg*4+0]*a2) * inv);
            o.y = f2bf((acc0[rg*4+1]*a1 + fb[slot + rg*4+1]*a2) * inv);
            o.z = f2bf((acc0[rg*4+2]*a1 + fb[slot + rg*4+2]*a2) * inv);
            o.w = f2bf((acc0[rg*4+3]*a1 + fb[slot + rg*4+3]*a2) * inv);
            *reinterpret_cast<ushort4*>(op + hd0) = o;
            o.x = f2bf((acc1[rg*4+0]*a1 + fb[slot + 16 + rg*4+0]*a2) * inv);
            o.y = f2bf((acc1[rg*4+1]*a1 + fb[slot + 16 + rg*4+1]*a2) * inv);
            o.z = f2bf((acc1[rg*4+2]*a1 + fb[slot + 16 + rg*4+2]*a2) * inv);
            o.w = f2bf((acc1[rg*4+3]*a1 + fb[slot + 16 + rg*4+3]*a2) * inv);
            *reinterpret_cast<ushort4*>(op + 32 + hd0) = o;
        }
    }
}

extern "C" void kernel_launch(void* const* d_in, const int* in_sizes, int n_in,
                              void* d_out, int out_size, void* d_ws, size_t ws_size,
                              hipStream_t stream)
{
    const float* x  = (const float*)d_in[0];
    const float* wq = (const float*)d_in[1];
    const float* bq = (const float*)d_in[2];
    const float* wk = (const float*)d_in[3];
    const float* bk = (const float*)d_in[4];
    const float* wv = (const float*)d_in[5];
    const float* bv = (const float*)d_in[6];
    const float* wo = (const float*)d_in[7];
    const float* bo = (const float*)d_in[8];
    float* out = (float*)d_out;

    char* ws = (char*)d_ws;
    ushort* xb    = (ushort*)(ws);                      // 8 MB  x bf16 (A for gemm0)
    ushort* wqkvT = (ushort*)(ws + (8ull  << 20));      // 6 MB  [3072][1024]
    ushort* woT   = (ushort*)(ws + (14ull << 20));      // 2 MB
    ushort* qw    = (ushort*)(ws + (16ull << 20));      // 8 MB  [bh][s][hd]
    ushort* kw    = (ushort*)(ws + (24ull << 20));      // 8 MB
    ushort* vtw   = (ushort*)(ws + (32ull << 20));      // 8 MB  [bh][hd][s] (written by gemm0)
    ushort* ao    = (ushort*)(ws + (40ull << 20));      // 8 MB

    // prep: 4 weight transposes + x convert in one launch
    prep<<<dim3(32, 32, 5), dim3(32, 8), 0, stream>>>(x, wq, wk, wv, wo, xb, wqkvT, woT);

    // QKV: M=4096, N=3072, K=1024 (768 blocks; V written directly transposed)
    gemm_bt<0, 4><<<768, 256, 0, stream>>>(xb, wqkvT, M_, 3072, 1024,
                                           qw, kw, vtw, bq, bk, bv, nullptr, nullptr);
    // attention: 512 blocks x 512 threads (8 waves: 2 key-halves x 4 q-waves)
    attn_kernel<<<dim3(16, 32), 512, 0, stream>>>(qw, kw, vtw, ao);
    // out proj: M=4096, N=1024, K=1024 (BN=64 -> 512 blocks -> 2 blocks/CU)
    gemm_bt<1, 2><<<512, 256, 0, stream>>>(ao, woT, M_, 1024, 1024,
                                           nullptr, nullptr, nullptr, nullptr, nullptr, nullptr,
                                           out, bo);
}

// Round 11
// 187.608 us; speedup vs baseline: 1.0561x; 1.0561x over previous
//
#include <hip/hip_runtime.h>
#include <hip/hip_bf16.h>

#define B_  2
#define S_  2048
#define D_  1024
#define H_  16
#define HD_ 64
#define M_  (B_*S_)   // 4096

using bf16x8 = __attribute__((ext_vector_type(8))) short;
using f32x4  = __attribute__((ext_vector_type(4))) float;
using f32x16 = __attribute__((ext_vector_type(16))) float;
using u32x4  = __attribute__((ext_vector_type(4))) unsigned int;
using uint2v = __attribute__((ext_vector_type(2))) unsigned int;

static __device__ __forceinline__ ushort f2bf(float f) {
    __hip_bfloat16 h = __float2bfloat16(f);
    return *reinterpret_cast<ushort*>(&h);
}
static __device__ __forceinline__ float max3f(float a, float b, float c) {
    return fmaxf(fmaxf(a, b), c);   // clang fuses to v_max3_f32
}
// native exp2 (v_exp_f32): args here are finite and <= +8, so no fixup path needed
static __device__ __forceinline__ float fexp2(float x) {
#if __has_builtin(__builtin_amdgcn_exp2f)
    return __builtin_amdgcn_exp2f(x);
#else
    return exp2f(x);
#endif
}
// branchless RNE bf16 pair-pack (valid for non-NaN inputs; P = exp2(<=8) is never NaN)
static __device__ __forceinline__ unsigned int pack_bf16(float p0, float p1) {
    unsigned int a = __float_as_uint(p0), b = __float_as_uint(p1);
    a += 0x7fffu + ((a >> 16) & 1u);
    b += 0x7fffu + ((b >> 16) & 1u);
    return (a >> 16) | (b & 0xffff0000u);
}

// async global->LDS, 16B per lane; LDS dest = wave-uniform base + lane*16
#define GLDS16(gp, lp) __builtin_amdgcn_global_load_lds( \
    (const __attribute__((address_space(1))) void*)(gp), \
    (__attribute__((address_space(3))) void*)(lp), 16, 0, 0)

// ------- prep: z<4 -> transpose one fp32 [1024][1024] weight to bf16 [C][R];
//         z==4 -> convert x fp32 -> bf16 (same layout). One launch total. -------
__global__ void prep(const float* __restrict__ x,
                     const float* __restrict__ wq, const float* __restrict__ wk,
                     const float* __restrict__ wv, const float* __restrict__ wo,
                     ushort* __restrict__ xb, ushort* __restrict__ wqkvT, ushort* __restrict__ woT) {
    const int z = blockIdx.z;
    if (z == 4) {
        int blk = blockIdx.y * 32 + blockIdx.x;          // 0..1023
        int tid = threadIdx.y * 32 + threadIdx.x;        // 0..255
        #pragma unroll
        for (int q = 0; q < 4; q++) {
            int i = ((q * 1024 + blk) * 256 + tid) * 4;  // covers 4M floats
            float4 v = *reinterpret_cast<const float4*>(x + i);
            ushort4 o;
            o.x = f2bf(v.x); o.y = f2bf(v.y); o.z = f2bf(v.z); o.w = f2bf(v.w);
            *reinterpret_cast<ushort4*>(xb + i) = o;
        }
        return;
    }
    const float* src = (z == 0) ? wq : (z == 1) ? wk : (z == 2) ? wv : wo;
    ushort* dst = (z < 3) ? (wqkvT + (size_t)z * 1024 * 1024) : woT;
    const int R = 1024, C = 1024;
    __shared__ float t[32][33];
    int c0 = blockIdx.x * 32, r0 = blockIdx.y * 32;
    int tx = threadIdx.x, ty = threadIdx.y;
    #pragma unroll
    for (int i = 0; i < 4; i++)
        t[ty + i*8][tx] = src[(size_t)(r0 + ty + i*8) * C + c0 + tx];
    __syncthreads();
    #pragma unroll
    for (int i = 0; i < 4; i++)
        dst[(size_t)(c0 + ty + i*8) * R + r0 + tx] = f2bf(t[tx][ty + i*8]);
}

// ---------------- GEMM: C = A(bf16 [M][K]) * Bt(bf16 [N][K])^T ----------------
// Round 11 = revert to round-8 config (measured best, 193.1 us): single-buffered
// BK=64, 32 KB LDS (3 blocks/CU), 32 MFMA per barrier, swizzled staging,
// XCD-chunked remap, block-uniform epilogue. BK=32 dbuf (round 10) was refuted:
// doubled iteration overhead ate the prefetch gain (+3 us GEMM).
// MODE 0 (NJ=4): QKV epilogue; V written directly transposed to [bh][hd][s].
// MODE 1 (NJ=2): fp32 out + bias, BN=64 -> 512 blocks.
template<int MODE, int NJ>
__launch_bounds__(256, 3)
__global__ void gemm_bt(const ushort* __restrict__ A, const ushort* __restrict__ Bt,
                        int Mdim, int Ndim, int Kdim,
                        ushort* __restrict__ qout, ushort* __restrict__ kout, ushort* __restrict__ vout,
                        const float* __restrict__ bq, const float* __restrict__ bk, const float* __restrict__ bv,
                        float* __restrict__ out, const float* __restrict__ bias)
{
    constexpr int BN = NJ * 32;
    __shared__ __align__(16) ushort As[128][64];   // 16 KB, swizzled 16B slots
    __shared__ __align__(16) ushort Bs[BN][64];    // 16 or 8 KB
    const int tid  = threadIdx.x;
    const int lane = tid & 63, wave = tid >> 6;
    const int wm = wave & 1, wn = wave >> 1;       // 2x2 waves
    // XCD-chunked remap: 8 consecutive lin -> 8 XCDs; contiguous super-tile per XCD.
    const int lin = blockIdx.x;
    const int xcd = lin & 7, idx = lin >> 3;
    int my, nx;
    if (MODE == 0) { my = (xcd >> 1) * 8 + idx / 12; nx = (xcd & 1) * 12 + idx % 12; }  // 8m x 12n per XCD
    else           { my = xcd * 4 + (idx >> 4);      nx = idx & 15; }                   // 4m x 16n per XCD
    const int m0 = my * 128, n0 = nx * BN;
    const int g = lane >> 4, c = lane & 15;

    f32x4 acc[4][NJ];
    #pragma unroll
    for (int i = 0; i < 4; i++)
        #pragma unroll
        for (int j = 0; j < NJ; j++) acc[i][j] = (f32x4){0.f, 0.f, 0.f, 0.f};

    // staging: 1 GLDS16 = 8 rows x 128B; A: 16 chunks, B: BN/8 chunks, over 4 waves.
    // LDS write is linear -> the GLOBAL source takes the inverse swizzle (rule #21).
    const int arow  = lane >> 3;                 // 0..7 within 8-row chunk
    const int aslot = (lane & 7) ^ arow;         // inverse-swizzled 16B slot
    const ushort* Ag = A  + (size_t)(m0 + arow) * Kdim + aslot * 8;
    const ushort* Bg = Bt + (size_t)(n0 + arow) * Kdim + aslot * 8;

    #pragma unroll 1
    for (int kt = 0; kt < Kdim; kt += 64) {
        #pragma unroll
        for (int p = 0; p < 4; p++) {
            int ch = wave + p * 4;               // 16 A-chunks over 4 waves
            GLDS16(Ag + (size_t)(ch*8) * Kdim + kt, &As[ch*8][0]);
        }
        #pragma unroll
        for (int p = 0; p < NJ; p++) {
            int ch = wave + p * 4;               // BN/8 B-chunks over 4 waves
            GLDS16(Bg + (size_t)(ch*8) * Kdim + kt, &Bs[ch*8][0]);
        }
        __syncthreads();
        #pragma unroll
        for (int ks = 0; ks < 2; ks++) {
            bf16x8 af[4], bfr[NJ];
            #pragma unroll
            for (int t = 0; t < 4; t++) {
                int sl = ((ks*4 + g) ^ (c & 7)) * 8;   // de-swizzle: row&7 == c&7
                af[t] = *reinterpret_cast<const bf16x8*>(&As[wm*64 + t*16 + c][sl]);
            }
            #pragma unroll
            for (int t = 0; t < NJ; t++) {
                int sl = ((ks*4 + g) ^ (c & 7)) * 8;
                bfr[t] = *reinterpret_cast<const bf16x8*>(&Bs[wn*(NJ*16) + t*16 + c][sl]);
            }
            #pragma unroll
            for (int i = 0; i < 4; i++)
                #pragma unroll
                for (int j = 0; j < NJ; j++)
                    acc[i][j] = __builtin_amdgcn_mfma_f32_16x16x32_bf16(af[i], bfr[j], acc[i][j], 0, 0, 0);
        }
        __syncthreads();
    }

    // ---- epilogue: which and h are BLOCK-uniform (tiles never straddle 1024-col lines) ----
    const float qscale = 0.125f * 1.4426950408889634f;  // att_scale * log2e (exp2 softmax)
    if (MODE == 0) {
        const int which = n0 >> 10;                      // 0=q 1=k 2=v (uniform)
        const int cc0 = (n0 & 1023) + wn*64;             // multiple of 64
        const int h = cc0 >> 6;                          // uniform head
        const int b = m0 >> 11;                          // uniform batch (128 | 2048)
        if (which == 2) {
            // ---- V: direct transposed store [bh][hd][s], ushort4 along s ----
            float bj[4];
            #pragma unroll
            for (int j = 0; j < 4; j++) bj[j] = bv[cc0 + j*16 + c];
            const int sbase = (m0 & 2047) + wm*64 + g*4;
            ushort* vb = vout + (size_t)(b*H_ + h) * HD_ * S_;
            #pragma unroll
            for (int i = 0; i < 4; i++) {
                int s0 = sbase + i*16;
                #pragma unroll
                for (int j = 0; j < 4; j++) {
                    int hd = j*16 + c;
                    ushort4 o;
                    o.x = f2bf(acc[i][j][0] + bj[j]);
                    o.y = f2bf(acc[i][j][1] + bj[j]);
                    o.z = f2bf(acc[i][j][2] + bj[j]);
                    o.w = f2bf(acc[i][j][3] + bj[j]);
                    *reinterpret_cast<ushort4*>(vb + (size_t)hd * S_ + s0) = o;
                }
            }
        } else {
            ushort* dst0 = (which == 0) ? qout : kout;
            const float* bp = (which == 0) ? bq : bk;
            const float scl = (which == 0) ? qscale : 1.f;
            float bj[4];
            #pragma unroll
            for (int j = 0; j < 4; j++) bj[j] = bp[cc0 + j*16 + c];
            #pragma unroll
            for (int i = 0; i < 4; i++) {
                #pragma unroll
                for (int r = 0; r < 4; r++) {
                    int row = m0 + wm*64 + i*16 + g*4 + r;   // C/D: row=(lane>>4)*4+reg
                    int s = row & 2047;
                    ushort* orow = dst0 + (((size_t)(b*H_ + h)) * S_ + s) * HD_;
                    #pragma unroll
                    for (int j = 0; j < 4; j++)
                        orow[j*16 + c] = f2bf((acc[i][j][r] + bj[j]) * scl);
                }
            }
        }
    } else {
        float bj[NJ];
        #pragma unroll
        for (int j = 0; j < NJ; j++) bj[j] = bias[n0 + wn*(NJ*16) + j*16 + c];
        #pragma unroll
        for (int i = 0; i < 4; i++)
            #pragma unroll
            for (int r = 0; r < 4; r++) {
                int row = m0 + wm*64 + i*16 + g*4 + r;
                float* orow = out + (size_t)row * Ndim + n0 + wn*(NJ*16);
                #pragma unroll
                for (int j = 0; j < NJ; j++)
                    orow[j*16 + c] = acc[i][j][r] + bj[j];
            }
    }
}

// ---------------- flash attention: in-block split-K + 2-tile interleave ----------------
// (unchanged from round-5..10 passing kernel: ~63-66 us steady-state)
__launch_bounds__(512, 4)
__global__ void attn_kernel(const ushort* __restrict__ Q, const ushort* __restrict__ K,
                            const ushort* __restrict__ Vt, ushort* __restrict__ O)
{
    __shared__ __align__(16) ushort Ks[2][2][64][64];   // [grp][buf][key][hd], swizzled
    __shared__ __align__(16) ushort Vs[2][2][64][64];   // [grp][buf][hd][key], swizzled
    const int tid = threadIdx.x, lane = tid & 63, w = tid >> 6;
    const int grp = w >> 2, wq4 = w & 3;                 // key-half group, q-wave within it
    const int q31 = lane & 31, hi = lane >> 5, x7 = lane & 7;

    // T1: group 4 consecutive bh per XCD so K/V (4*512KB=2MB) stay L2-resident
    int lin = blockIdx.x + gridDim.x * blockIdx.y;   // 0..511
    int xcd = lin & 7, idx = lin >> 3;
    int bh = xcd * 4 + (idx & 3);
    int qb = idx >> 2;                                // 0..15
    const int q0 = qb * 128;
    const int kt_base = grp * 1024;
    const ushort* Kp = K  + (size_t)bh * S_ * HD_;   // [s][hd]
    const ushort* Vp = Vt + (size_t)bh * HD_ * S_;   // [hd][s]

    // Q B-fragments (pre-scaled by 0.125*log2e): B[col=q31][k = hi*8+j], 4 hd-chunks
    bf16x8 qf[4];
    #pragma unroll
    for (int c4 = 0; c4 < 4; c4++)
        qf[c4] = *reinterpret_cast<const bf16x8*>(
            Q + (size_t)bh * S_ * HD_ + (size_t)(q0 + wq4*32 + q31) * HD_ + c4*16 + hi*8);

    f32x16 acc0, acc1;          // O^T: row = hd', col = q31 (acc0: hd 0-31, acc1: 32-63)
    #pragma unroll
    for (int r = 0; r < 16; r++) { acc0[r] = 0.f; acc1[r] = 0.f; }
    float m_i = -INFINITY, l_i = 0.f;

    // staging geometry: per wave 8 rows x 128B per GLDS16; swizzle folded into global src
    const int srow  = lane >> 3;              // 0..7 within chunk
    const int sslot = (lane & 7) ^ srow;      // inverse-swizzled 16B slot
    const ushort* kg = Kp + (size_t)srow * HD_ + sslot * 8;
    const ushort* vg = Vp + (size_t)srow * S_  + sslot * 8;

    auto stage = [&](int buf, int kt) {       // group's 4 waves cover 8 chunks x 8 rows
        #pragma unroll
        for (int p = 0; p < 2; p++) {
            int ch = wq4 + p * 4;
            GLDS16(kg + (size_t)(kt + ch*8) * HD_, &Ks[grp][buf][ch*8][0]);
            GLDS16(vg + (size_t)(ch*8) * S_ + kt,  &Vs[grp][buf][ch*8][0]);
        }
    };

    // softmax + in-register repack for one 32-key tile
    auto softmax_pack = [&](const f32x16& st, bf16x8& pf0, bf16x8& pf1) {
        float g0 = max3f(st[0],  st[1],  st[2]);
        float g1 = max3f(st[3],  st[4],  st[5]);
        float g2 = max3f(st[6],  st[7],  st[8]);
        float g3 = max3f(st[9],  st[10], st[11]);
        float g4 = max3f(st[12], st[13], st[14]);
        float pm = fmaxf(max3f(g0, g1, g2), max3f(g3, g4, st[15]));
#if __has_builtin(__builtin_amdgcn_permlane32_swap)
        {
            uint2v r = __builtin_amdgcn_permlane32_swap(__float_as_uint(pm), __float_as_uint(pm), false, false);
            pm = fmaxf(__uint_as_float(r.x), __uint_as_float(r.y));
        }
#else
        pm = fmaxf(pm, __shfl_xor(pm, 32));
#endif
        if (__any(pm > m_i + 8.f)) {          // T13 defer-max (exp2 domain)
            float mnew = fmaxf(m_i, pm);
            float al = fexp2(m_i - mnew);
            l_i *= al;
            #pragma unroll
            for (int r = 0; r < 16; r++) { acc0[r] *= al; acc1[r] *= al; }
            m_i = mnew;
        }
        float rs = 0.f;
        unsigned int dd[8];
        #pragma unroll
        for (int r2 = 0; r2 < 8; r2++) {
            float p0 = fexp2(st[r2*2]     - m_i);
            float p1 = fexp2(st[r2*2 + 1] - m_i);
            rs += p0 + p1;
            dd[r2] = pack_bf16(p0, p1);
        }
#if __has_builtin(__builtin_amdgcn_permlane32_swap)
        {
            uint2v r = __builtin_amdgcn_permlane32_swap(__float_as_uint(rs), __float_as_uint(rs), false, false);
            rs = __uint_as_float(r.x) + __uint_as_float(r.y);
        }
#else
        rs += __shfl_xor(rs, 32);
#endif
        l_i += rs;
        u32x4 t0, t1;
#if __has_builtin(__builtin_amdgcn_permlane32_swap)
        {
            uint2v s02 = __builtin_amdgcn_permlane32_swap(dd[0], dd[2], false, false);
            uint2v s13 = __builtin_amdgcn_permlane32_swap(dd[1], dd[3], false, false);
            uint2v s46 = __builtin_amdgcn_permlane32_swap(dd[4], dd[6], false, false);
            uint2v s57 = __builtin_amdgcn_permlane32_swap(dd[5], dd[7], false, false);
            t0 = (u32x4){s02.x, s13.x, s02.y, s13.y};
            t1 = (u32x4){s46.x, s57.x, s46.y, s57.y};
        }
#else
        {
            unsigned int ee[8];
            #pragma unroll
            for (int r2 = 0; r2 < 8; r2++)
                ee[r2] = (unsigned int)__shfl_xor((int)dd[r2], 32);
            t0 = (u32x4){ hi ? ee[2] : dd[0], hi ? ee[3] : dd[1],
                          hi ? dd[2] : ee[0], hi ? dd[3] : ee[1] };
            t1 = (u32x4){ hi ? ee[6] : dd[4], hi ? ee[7] : dd[5],
                          hi ? dd[6] : ee[4], hi ? dd[7] : ee[5] };
        }
#endif
        pf0 = *reinterpret_cast<bf16x8*>(&t0);
        pf1 = *reinterpret_cast<bf16x8*>(&t1);
    };

    auto compute64 = [&](int buf) {
        const ushort (*ks)[64] = Ks[grp][buf];
        const ushort (*vs)[64] = Vs[grp][buf];
        // ---- QK^T for BOTH 32-key tiles up front (MFMA latency hides under sm(t0)) ----
        f32x16 st0, st1;
        #pragma unroll
        for (int r = 0; r < 16; r++) { st0[r] = 0.f; st1[r] = 0.f; }
        __builtin_amdgcn_s_setprio(1);
        #pragma unroll
        for (int c4 = 0; c4 < 4; c4++) {
            bf16x8 kf = *reinterpret_cast<const bf16x8*>(&ks[q31][((c4*2 + hi) ^ x7) * 8]);
            st0 = __builtin_amdgcn_mfma_f32_32x32x16_bf16(kf, qf[c4], st0, 0, 0, 0);
        }
        #pragma unroll
        for (int c4 = 0; c4 < 4; c4++) {
            bf16x8 kf = *reinterpret_cast<const bf16x8*>(&ks[32 + q31][((c4*2 + hi) ^ x7) * 8]);
            st1 = __builtin_amdgcn_mfma_f32_32x32x16_bf16(kf, qf[c4], st1, 0, 0, 0);
        }
        __builtin_amdgcn_s_setprio(0);

        // ---- tile 0: softmax (overlaps st1 MFMA), then PV ----
        bf16x8 pf0, pf1;
        softmax_pack(st0, pf0, pf1);
        {
            bf16x8 vf0 = *reinterpret_cast<const bf16x8*>(&vs[q31]     [((0 + hi) ^ x7) * 8]);
            bf16x8 vf1 = *reinterpret_cast<const bf16x8*>(&vs[q31]     [((2 + hi) ^ x7) * 8]);
            bf16x8 vf2 = *reinterpret_cast<const bf16x8*>(&vs[32 + q31][((0 + hi) ^ x7) * 8]);
            bf16x8 vf3 = *reinterpret_cast<const bf16x8*>(&vs[32 + q31][((2 + hi) ^ x7) * 8]);
            __builtin_amdgcn_s_setprio(1);
            acc0 = __builtin_amdgcn_mfma_f32_32x32x16_bf16(vf0, pf0, acc0, 0, 0, 0);
            acc0 = __builtin_amdgcn_mfma_f32_32x32x16_bf16(vf1, pf1, acc0, 0, 0, 0);
            acc1 = __builtin_amdgcn_mfma_f32_32x32x16_bf16(vf2, pf0, acc1, 0, 0, 0);
            acc1 = __builtin_amdgcn_mfma_f32_32x32x16_bf16(vf3, pf1, acc1, 0, 0, 0);
            __builtin_amdgcn_s_setprio(0);
        }
        // ---- tile 1: softmax (overlaps PV(t0) MFMA), then PV ----
        softmax_pack(st1, pf0, pf1);
        {
            bf16x8 vf0 = *reinterpret_cast<const bf16x8*>(&vs[q31]     [((4 + hi) ^ x7) * 8]);
            bf16x8 vf1 = *reinterpret_cast<const bf16x8*>(&vs[q31]     [((6 + hi) ^ x7) * 8]);
            bf16x8 vf2 = *reinterpret_cast<const bf16x8*>(&vs[32 + q31][((4 + hi) ^ x7) * 8]);
            bf16x8 vf3 = *reinterpret_cast<const bf16x8*>(&vs[32 + q31][((6 + hi) ^ x7) * 8]);
            __builtin_amdgcn_s_setprio(1);
            acc0 = __builtin_amdgcn_mfma_f32_32x32x16_bf16(vf0, pf0, acc0, 0, 0, 0);
            acc0 = __builtin_amdgcn_mfma_f32_32x32x16_bf16(vf1, pf1, acc0, 0, 0, 0);
            acc1 = __builtin_amdgcn_mfma_f32_32x32x16_bf16(vf2, pf0, acc1, 0, 0, 0);
            acc1 = __builtin_amdgcn_mfma_f32_32x32x16_bf16(vf3, pf1, acc1, 0, 0, 0);
            __builtin_amdgcn_s_setprio(0);
        }
    };

    // ---- 2-phase pipelined main loop over this group's 1024 keys (16 x 64) ----
    stage(0, kt_base);
    __syncthreads();
    #pragma unroll 1
    for (int it = 0; it < 15; ++it) {
        stage((it & 1) ^ 1, kt_base + (it + 1) * 64);
        compute64(it & 1);
        __syncthreads();                 // drains vmcnt (next tile arrived) + protects reuse
    }
    compute64(1);

    // ---- cross-group merge via LDS (lane-aligned: partner lane = same (q, hd-set)) ----
    __syncthreads();                     // everyone done reading K/V LDS
    float* fb = (wq4 < 2) ? reinterpret_cast<float*>(&Ks[0][0][0][0])
                          : reinterpret_cast<float*>(&Vs[0][0][0][0]);
    const int slot = ((wq4 & 1) * 64 + lane) * 35;   // 35: odd stride, conflict-light
    if (grp == 1) {
        #pragma unroll
        for (int r = 0; r < 16; r++) { fb[slot + r] = acc0[r]; fb[slot + 16 + r] = acc1[r]; }
        fb[slot + 32] = m_i;
        fb[slot + 33] = l_i;
    }
    __syncthreads();
    if (grp == 0) {
        float m2 = fb[slot + 32], l2 = fb[slot + 33];
        float mm = fmaxf(m_i, m2);
        float a1 = fexp2(m_i - mm), a2 = fexp2(m2 - mm);
        float inv = 1.f / (l_i * a1 + l2 * a2);
        const int b = bh >> 4, h = bh & 15;
        const int s = q0 + wq4*32 + q31;
        ushort* op = O + (size_t)(b*S_ + s) * 1024 + h*64;
        #pragma unroll
        for (int rg = 0; rg < 4; rg++) {
            int hd0 = rg*8 + hi*4;
            ushort4 o;
            o.x = f2bf((acc0[rg*4+0]*a1 + fb[slot + rg*4+0]*a2) * inv);
            o.y = f2bf((acc0[rg*4+1]*a1 + fb[slot + rg*4+1]*a2) * inv);
            o.z = f2bf((acc0[rg*4+2]*a1 + fb[slot + rg*4+2]*a2) * inv);
            o.w = f2bf((acc0[rg*4+3]*a1 + fb[slot + rg*4+3]*a2) * inv);
            *reinterpret_cast<ushort4*>(op + hd0) = o;
            o.x = f2bf((acc1[rg*4+0]*a1 + fb[slot + 16 + rg*4+0]*a2) * inv);
            o.y = f2bf((acc1[rg*4+1]*a1 + fb[slot + 16 + rg*4+1]*a2) * inv);
            o.z = f2bf((acc1[rg*4+2]*a1 + fb[slot + 16 + rg*4+2]*a2) * inv);
            o.w = f2bf((acc1[rg*4+3]*a1 + fb[slot + 16 + rg*4+3]*a2) * inv);
            *reinterpret_cast<ushort4*>(op + 32 + hd0) = o;
        }
    }
}

extern "C" void kernel_launch(void* const* d_in, const int* in_sizes, int n_in,
                              void* d_out, int out_size, void* d_ws, size_t ws_size,
                              hipStream_t stream)
{
    const float* x  = (const float*)d_in[0];
    const float* wq = (const float*)d_in[1];
    const float* bq = (const float*)d_in[2];
    const float* wk = (const float*)d_in[3];
    const float* bk = (const float*)d_in[4];
    const float* wv = (const float*)d_in[5];
    const float* bv = (const float*)d_in[6];
    const float* wo = (const float*)d_in[7];
    const float* bo = (const float*)d_in[8];
    float* out = (float*)d_out;

    char* ws = (char*)d_ws;
    ushort* xb    = (ushort*)(ws);                      // 8 MB  x bf16 (A for gemm0)
    ushort* wqkvT = (ushort*)(ws + (8ull  << 20));      // 6 MB  [3072][1024]
    ushort* woT   = (ushort*)(ws + (14ull << 20));      // 2 MB
    ushort* qw    = (ushort*)(ws + (16ull << 20));      // 8 MB  [bh][s][hd]
    ushort* kw    = (ushort*)(ws + (24ull << 20));      // 8 MB
    ushort* vtw   = (ushort*)(ws + (32ull << 20));      // 8 MB  [bh][hd][s] (written by gemm0)
    ushort* ao    = (ushort*)(ws + (40ull << 20));      // 8 MB

    // prep: 4 weight transposes + x convert in one launch
    prep<<<dim3(32, 32, 5), dim3(32, 8), 0, stream>>>(x, wq, wk, wv, wo, xb, wqkvT, woT);

    // QKV: M=4096, N=3072, K=1024 (768 blocks; V written directly transposed)
    gemm_bt<0, 4><<<768, 256, 0, stream>>>(xb, wqkvT, M_, 3072, 1024,
                                           qw, kw, vtw, bq, bk, bv, nullptr, nullptr);
    // attention: 512 blocks x 512 threads (8 waves: 2 key-halves x 4 q-waves)
    attn_kernel<<<dim3(16, 32), 512, 0, stream>>>(qw, kw, vtw, ao);
    // out proj: M=4096, N=1024, K=1024 (BN=64 -> 512 blocks -> 2 blocks/CU)
    gemm_bt<1, 2><<<512, 256, 0, stream>>>(ao, woT, M_, 1024, 1024,
                                           nullptr, nullptr, nullptr, nullptr, nullptr, nullptr,
                                           out, bo);
}